// Round 1
// baseline (14353.264 us; speedup 1.0000x reference)
//
#include <hip/hip_runtime.h>
#include <hip/hip_bf16.h>
#include <stdint.h>

// ---------------- types / helpers ----------------
typedef __bf16 bf16x8 __attribute__((ext_vector_type(8)));
typedef float  f32x4  __attribute__((ext_vector_type(4)));

#define MFMA_B16(A_,B_,C_) __builtin_amdgcn_mfma_f32_16x16x32_bf16((A_),(B_),(C_),0,0,0)

static constexpr int TT = 200;   // time steps

static __device__ __forceinline__ float sig_f(float x){ return 1.f/(1.f+__expf(-x)); }
static __device__ __forceinline__ float tanh_f(float x){
  float e = __expf(-2.f*fabsf(x));
  float t = (1.f-e)/(1.f+e);
  return x<0.f ? -t : t;
}

// load 8 consecutive f32 and round to bf16x8 (MFMA A-fragment from f32 source)
static __device__ __forceinline__ bf16x8 ld8f_bf16(const float* p){
  float4 a = *(const float4*)p;
  float4 b = *(const float4*)(p+4);
  bf16x8 v;
  v[0]=(__bf16)a.x; v[1]=(__bf16)a.y; v[2]=(__bf16)a.z; v[3]=(__bf16)a.w;
  v[4]=(__bf16)b.x; v[5]=(__bf16)b.y; v[6]=(__bf16)b.z; v[7]=(__bf16)b.w;
  return v;
}

// XOR-swizzled LDS addressing: breaks the 16-way bank conflict of row-major
// tiles read 16B-per-lane down a column (cdna guide §6 G4).
static __device__ __forceinline__ int swz_off(int row, int col_bytes, int strideB){
  return (row*strideB + col_bytes) ^ ((row&7)<<4);
}
static __device__ __forceinline__ bf16x8 lds_rdA(const __bf16* buf, int row, int kt, int lq, int strideB){
  int off = swz_off(row, kt*64 + lq*16, strideB);
  return *(const bf16x8*)((const char*)buf + off);
}
static __device__ __forceinline__ void lds_wr(__bf16* buf, int row, int dim, int strideB, float v){
  int off = swz_off(row, dim*2, strideB);
  *(__bf16*)((char*)buf + off) = (__bf16)v;
}

// ---------------- K0: f32 -> bf16 weight conversion ----------------
__global__ void cvt_bf16(const float* __restrict__ s, __bf16* __restrict__ d, int n){
  int i = blockIdx.x*blockDim.x + threadIdx.x;
  int st = gridDim.x*blockDim.x;
  for(; i<n; i+=st) d[i] = (__bf16)s[i];
}

// ---------------- K1: encoder scans (4 GRU cells, persistent) ----------------
// grid (16,4): x = batch tile (32 rows), y = cell {0:gf,1:gb,2:cf,3:cb}
// block 512 = 8 waves; wave w owns hidden dims [w*32, w*32+32) for all 3 gates.
struct EncArgs {
  const float* x;               // [512][200][256] f32
  const __bf16* wih[4];         // [768][256] bf16
  const __bf16* whh[4];         // [768][256] bf16
  const float* bih[4];
  const float* bhh[4];
  __bf16* henc;                 // [200][512][512]  (cols 0..255 = hcf[t], 256..511 = hcb rev)
  float*  hencg;                // [512][512]       (cols 0..255 = hgf, 256..511 = hgb)
};

__global__ __launch_bounds__(512,2) void enc_scan(EncArgs Ae){
  const int tid = threadIdx.x;
  const int w = tid>>6, l = tid&63, lr = l&15, lq = l>>4;
  const int cell = blockIdx.y;
  const bool fwd = (cell==0)||(cell==2);
  const bool isC = cell>=2;
  const int b0 = blockIdx.x*32;
  const __bf16* __restrict__ Wi = Ae.wih[cell];
  const __bf16* __restrict__ Wh = Ae.whh[cell];

  __shared__ __align__(16) __bf16 hbuf[2][32*256];
  for(int i=tid;i<32*256;i+=512) hbuf[0][i] = (__bf16)0.f;

  const int dim0 = w*32;
  // B-fragment element offsets (W is [768][256] row-major = B^T): lane reads W[n][k..k+8)
  int bo[3][2];
  #pragma unroll
  for(int g=0;g<3;g++)
    #pragma unroll
    for(int jt=0;jt<2;jt++)
      bo[g][jt] = (g*256 + dim0 + jt*16 + lr)*256 + lq*8;

  float brz0[2], brz1[2], bin[2], bhn[2];
  #pragma unroll
  for(int jt=0;jt<2;jt++){
    int d = dim0 + jt*16 + lr;
    brz0[jt] = Ae.bih[cell][d]     + Ae.bhh[cell][d];
    brz1[jt] = Ae.bih[cell][256+d] + Ae.bhh[cell][256+d];
    bin[jt]  = Ae.bih[cell][512+d];
    bhn[jt]  = Ae.bhh[cell][512+d];
  }

  size_t xrow[2];
  #pragma unroll
  for(int mt=0;mt<2;mt++) xrow[mt] = (size_t)(b0 + mt*16 + lr)*TT*256;

  f32x4 hold[2][2];
  #pragma unroll
  for(int mt=0;mt<2;mt++){ hold[mt][0]=(f32x4){}; hold[mt][1]=(f32x4){}; }

  __syncthreads();
  int p = 0;
  #pragma unroll 1
  for(int s=0;s<TT;s++){
    const int tx = fwd ? s : (TT-1-s);
    f32x4 aR[2][2]={}, aZ[2][2]={}, aI[2][2]={}, aH[2][2]={};
    const __bf16* hb = hbuf[p];
    #pragma unroll 2
    for(int kt=0;kt<8;kt++){
      bf16x8 ax[2], ah[2];
      #pragma unroll
      for(int mt=0;mt<2;mt++){
        ax[mt] = ld8f_bf16(Ae.x + xrow[mt] + (size_t)tx*256 + kt*32 + lq*8);
        ah[mt] = lds_rdA(hb, mt*16+lr, kt, lq, 512);
      }
      #pragma unroll
      for(int g=0;g<3;g++){
        #pragma unroll
        for(int jt=0;jt<2;jt++){
          bf16x8 bi = *(const bf16x8*)(Wi + bo[g][jt] + kt*32);
          bf16x8 bh = *(const bf16x8*)(Wh + bo[g][jt] + kt*32);
          #pragma unroll
          for(int mt=0;mt<2;mt++){
            if(g==0){ aR[mt][jt]=MFMA_B16(ax[mt],bi,aR[mt][jt]); aR[mt][jt]=MFMA_B16(ah[mt],bh,aR[mt][jt]); }
            else if(g==1){ aZ[mt][jt]=MFMA_B16(ax[mt],bi,aZ[mt][jt]); aZ[mt][jt]=MFMA_B16(ah[mt],bh,aZ[mt][jt]); }
            else { aI[mt][jt]=MFMA_B16(ax[mt],bi,aI[mt][jt]); aH[mt][jt]=MFMA_B16(ah[mt],bh,aH[mt][jt]); }
          }
        }
      }
    }
    __bf16* wb = hbuf[1-p];
    #pragma unroll
    for(int mt=0;mt<2;mt++)
      #pragma unroll
      for(int jt=0;jt<2;jt++)
        #pragma unroll
        for(int rr=0;rr<4;rr++){
          float r = sig_f(aR[mt][jt][rr] + brz0[jt]);
          float z = sig_f(aZ[mt][jt][rr] + brz1[jt]);
          float nn= tanh_f(aI[mt][jt][rr] + bin[jt] + r*(aH[mt][jt][rr] + bhn[jt]));
          float h = (1.f-z)*nn + z*hold[mt][jt][rr];
          h = fminf(h, 5.f);                      // clamp(max=CLIP)
          hold[mt][jt][rr] = h;
          int row = mt*16 + lq*4 + rr;
          int d   = dim0 + jt*16 + lr;
          lds_wr(wb, row, d, 512, h);
          if(isC)
            Ae.henc[((size_t)tx*512 + (b0+row))*512 + (cell==3?256:0) + d] = (__bf16)h;
        }
    __syncthreads();
    p ^= 1;
  }
  if(!isC){
    #pragma unroll
    for(int mt=0;mt<2;mt++)
      for(int jt=0;jt<2;jt++)
        for(int rr=0;rr<4;rr++){
          int row = mt*16 + lq*4 + rr;
          int d   = dim0 + jt*16 + lr;
          Ae.hencg[(size_t)(b0+row)*512 + (cell==1?256:0) + d] = hold[mt][jt][rr];
        }
  }
}

// ---------------- K2: g0 head (f32 VALU) ----------------
__global__ void g0_kernel(const float* __restrict__ hencg,
                          const float* __restrict__ Wm, const float* __restrict__ bm,
                          const float* __restrict__ Wv, const float* __restrict__ bv,
                          const float* __restrict__ eps,
                          float* __restrict__ o_mean, float* __restrict__ o_logv,
                          float* __restrict__ g0){
  int j = blockIdx.x*blockDim.x + threadIdx.x;    // 512*256
  int b = j>>8, d = j&255;
  const float4* hp=(const float4*)(hencg + (size_t)b*512);
  const float4* mp=(const float4*)(Wm + (size_t)d*512);
  const float4* vp=(const float4*)(Wv + (size_t)d*512);
  float am=0.f, av=0.f;
  #pragma unroll 4
  for(int k=0;k<128;k++){
    float4 h=hp[k], m=mp[k], v=vp[k];
    am += h.x*m.x + h.y*m.y + h.z*m.z + h.w*m.w;
    av += h.x*v.x + h.y*v.y + h.z*v.z + h.w*v.w;
  }
  float mean = am + bm[d];
  float ev   = __expf(av + bv[d]) + 1e-4f;
  float lv   = __logf(ev);
  o_mean[j]=mean; o_logv[j]=lv;
  g0[j] = eps[j]*sqrtf(ev) + mean;                // eps*exp(0.5*logv)+mean
}

// ---------------- K3: gi_ct = h_enc_c @ Wih_ct[:,:512]^T  (bf16 MFMA GEMM) ----------------
// [102400 x 512] @ [512 x 384] -> bf16 [102400 x 384]
__global__ __launch_bounds__(256,2) void gict_gemm(const __bf16* __restrict__ henc,
                                                   const __bf16* __restrict__ wct,   // [384][576]
                                                   __bf16* __restrict__ gict){
  const int tid=threadIdx.x, w=tid>>6, l=tid&63, lr=l&15, lq=l>>4;
  const int m0 = blockIdx.x*8 + w*2;
  bf16x8 a[2][16];
  #pragma unroll
  for(int m=0;m<2;m++){
    const __bf16* ap = henc + (size_t)((m0+m)*16 + lr)*512 + lq*8;
    #pragma unroll
    for(int kt=0;kt<16;kt++) a[m][kt] = *(const bf16x8*)(ap + kt*32);
  }
  #pragma unroll 1
  for(int nt=0;nt<24;nt++){
    f32x4 c0={}, c1={};
    const __bf16* bp = wct + (size_t)(nt*16+lr)*576 + lq*8;   // k in [0,512)
    #pragma unroll
    for(int kt=0;kt<16;kt++){
      bf16x8 bb = *(const bf16x8*)(bp + kt*32);
      c0 = MFMA_B16(a[0][kt], bb, c0);
      c1 = MFMA_B16(a[1][kt], bb, c1);
    }
    #pragma unroll
    for(int rr=0;rr<4;rr++){
      gict[(size_t)((m0+0)*16 + lq*4 + rr)*384 + nt*16 + lr] = (__bf16)c0[rr];
      gict[(size_t)((m0+1)*16 + lq*4 + rr)*384 + nt*16 + lr] = (__bf16)c1[rr];
    }
  }
}

// ---------------- K4: generator scan (persistent, 16 blocks) ----------------
struct GenArgs{
  const __bf16 *wih_ct, *whh_ct, *wih_gn, *whh_gn, *w_um, *w_uv, *w_f;
  const float  *bih_ct, *bhh_ct, *bih_gn, *bhh_gn, *b_um, *b_uv, *b_f;
  const __bf16* gih;    // [200][512][384] precomputed henc part of ct-gi
  const float*  g0;     // [512][256]
  const float*  eps_u;  // [512][200][64]
  float *o_um, *o_ul, *o_f;   // d_out sections, each [512][200][64]
};

__global__ __launch_bounds__(512,2) void gen_scan(GenArgs Ag){
  const int tid=threadIdx.x, w=tid>>6, l=tid&63, lr=l&15, lq=l>>4;
  const int b0 = blockIdx.x*32;
  __shared__ __align__(16) __bf16 hc[2][32*128];
  __shared__ __align__(16) __bf16 gbuf[2][32*256];
  __shared__ __align__(16) __bf16 fbuf[2][32*64];
  __shared__ __align__(16) __bf16 ubuf[32*64];
  __shared__ float um_p[32*64], ul_p[32*64];

  const int dc = w*16 + lr;        // ct hidden dim owned by this lane
  const int du = (w&3)*16 + lr;    // um/uv/f dim

  int o_ihct[3], o_hhct[3], o_ihgn[3][2], o_hhgn[3][2];
  #pragma unroll
  for(int g=0;g<3;g++){
    int n = g*128 + dc;
    o_ihct[g] = n*576 + 512 + lq*8;   // f-columns of Wih_ct
    o_hhct[g] = n*128 + lq*8;
  }
  #pragma unroll
  for(int g=0;g<3;g++)
    #pragma unroll
    for(int jt=0;jt<2;jt++){
      int n = g*256 + w*32 + jt*16 + lr;
      o_ihgn[g][jt] = n*64  + lq*8;
      o_hhgn[g][jt] = n*256 + lq*8;
    }
  const int o_u  = du*128 + lq*8;
  const int o_fw = du*256 + lq*8;

  float bct_rz0 = Ag.bih_ct[dc]     + Ag.bhh_ct[dc];
  float bct_rz1 = Ag.bih_ct[128+dc] + Ag.bhh_ct[128+dc];
  float bct_in  = Ag.bih_ct[256+dc];
  float bct_hn  = Ag.bhh_ct[256+dc];
  float bgn_rz0[2], bgn_rz1[2], bgn_in[2], bgn_hn[2];
  #pragma unroll
  for(int jt=0;jt<2;jt++){
    int d = w*32 + jt*16 + lr;
    bgn_rz0[jt] = Ag.bih_gn[d]     + Ag.bhh_gn[d];
    bgn_rz1[jt] = Ag.bih_gn[256+d] + Ag.bhh_gn[256+d];
    bgn_in[jt]  = Ag.bih_gn[512+d];
    bgn_hn[jt]  = Ag.bhh_gn[512+d];
  }
  const float buv = (w<4)? Ag.b_um[du] : Ag.b_uv[du];
  const float bff = Ag.b_f[du];

  // ---- prologue: g_old <- g0, h_c <- 0, f <- f0 = g0@W_f^T+b_f ----
  f32x4 g_old[2][2], hc_old[2];
  hc_old[0]=(f32x4){}; hc_old[1]=(f32x4){};
  #pragma unroll
  for(int mt=0;mt<2;mt++)
    #pragma unroll
    for(int jt=0;jt<2;jt++)
      #pragma unroll
      for(int rr=0;rr<4;rr++){
        int row = mt*16 + lq*4 + rr;
        int d   = w*32 + jt*16 + lr;
        float v = Ag.g0[(size_t)(b0+row)*256 + d];
        g_old[mt][jt][rr] = v;
        lds_wr(gbuf[0], row, d, 512, v);
      }
  for(int i=tid;i<32*128;i+=512) hc[0][i] = (__bf16)0.f;
  __syncthreads();
  if(w<4){
    f32x4 fa[2]={};
    #pragma unroll
    for(int kt=0;kt<8;kt++){
      bf16x8 bb = *(const bf16x8*)(Ag.w_f + o_fw + kt*32);
      #pragma unroll
      for(int mt=0;mt<2;mt++){
        bf16x8 aa = lds_rdA(gbuf[0], mt*16+lr, kt, lq, 512);
        fa[mt] = MFMA_B16(aa, bb, fa[mt]);
      }
    }
    #pragma unroll
    for(int mt=0;mt<2;mt++)
      for(int rr=0;rr<4;rr++)
        lds_wr(fbuf[0], mt*16+lq*4+rr, du, 128, fa[mt][rr]+bff);
  }
  __syncthreads();

  int pc=0, pg=0, pf=0;
  #pragma unroll 1
  for(int t=0;t<TT;t++){
    // ---- P1: controller GRU (input = [henc(precomputed gi) , f]) ----
    float gih[3][2][4];
    #pragma unroll
    for(int g=0;g<3;g++)
      #pragma unroll
      for(int mt=0;mt<2;mt++)
        #pragma unroll
        for(int rr=0;rr<4;rr++){
          int row = mt*16 + lq*4 + rr;
          gih[g][mt][rr] = (float)Ag.gih[((size_t)t*512 + b0 + row)*384 + g*128 + dc];
        }
    f32x4 cR[2]={}, cZ[2]={}, cI[2]={}, cH[2]={};
    #pragma unroll
    for(int kt=0;kt<2;kt++){
      bf16x8 af[2];
      #pragma unroll
      for(int mt=0;mt<2;mt++) af[mt] = lds_rdA(fbuf[pf], mt*16+lr, kt, lq, 128);
      #pragma unroll
      for(int g=0;g<3;g++){
        bf16x8 bb = *(const bf16x8*)(Ag.wih_ct + o_ihct[g] + kt*32);
        #pragma unroll
        for(int mt=0;mt<2;mt++){
          if(g==0)      cR[mt]=MFMA_B16(af[mt],bb,cR[mt]);
          else if(g==1) cZ[mt]=MFMA_B16(af[mt],bb,cZ[mt]);
          else          cI[mt]=MFMA_B16(af[mt],bb,cI[mt]);
        }
      }
    }
    #pragma unroll
    for(int kt=0;kt<4;kt++){
      bf16x8 ah[2];
      #pragma unroll
      for(int mt=0;mt<2;mt++) ah[mt] = lds_rdA(hc[pc], mt*16+lr, kt, lq, 256);
      #pragma unroll
      for(int g=0;g<3;g++){
        bf16x8 bb = *(const bf16x8*)(Ag.whh_ct + o_hhct[g] + kt*32);
        #pragma unroll
        for(int mt=0;mt<2;mt++){
          if(g==0)      cR[mt]=MFMA_B16(ah[mt],bb,cR[mt]);
          else if(g==1) cZ[mt]=MFMA_B16(ah[mt],bb,cZ[mt]);
          else          cH[mt]=MFMA_B16(ah[mt],bb,cH[mt]);
        }
      }
    }
    #pragma unroll
    for(int mt=0;mt<2;mt++)
      #pragma unroll
      for(int rr=0;rr<4;rr++){
        float r = sig_f(cR[mt][rr] + gih[0][mt][rr] + bct_rz0);
        float z = sig_f(cZ[mt][rr] + gih[1][mt][rr] + bct_rz1);
        float nn= tanh_f(cI[mt][rr] + gih[2][mt][rr] + bct_in + r*(cH[mt][rr] + bct_hn));
        float h = (1.f-z)*nn + z*hc_old[mt][rr];
        h = fminf(fmaxf(h, 0.f), 5.f);
        hc_old[mt][rr] = h;
        lds_wr(hc[1-pc], mt*16+lq*4+rr, dc, 256, h);
      }
    __syncthreads();

    // ---- P2: um (waves 0-3) / ul (waves 4-7) ----
    {
      const __bf16* WU = (w<4)? Ag.w_um : Ag.w_uv;
      f32x4 ua[2]={};
      #pragma unroll
      for(int kt=0;kt<4;kt++){
        bf16x8 bb = *(const bf16x8*)(WU + o_u + kt*32);
        #pragma unroll
        for(int mt=0;mt<2;mt++){
          bf16x8 aa = lds_rdA(hc[1-pc], mt*16+lr, kt, lq, 256);
          ua[mt] = MFMA_B16(aa, bb, ua[mt]);
        }
      }
      float* plane = (w<4)? um_p : ul_p;
      float* gout  = (w<4)? Ag.o_um : Ag.o_ul;
      #pragma unroll
      for(int mt=0;mt<2;mt++)
        #pragma unroll
        for(int rr=0;rr<4;rr++){
          int row = mt*16 + lq*4 + rr;
          float v = ua[mt][rr] + buv;
          plane[row*64 + du] = v;
          gout[((size_t)(b0+row)*TT + t)*64 + du] = v;
        }
    }
    __syncthreads();

    // ---- P3: u = eps*exp(0.5*ul)+um -> bf16 LDS ----
    {
      int i0 = tid*4;
      #pragma unroll
      for(int q=0;q<4;q++){
        int i = i0+q; int row = i>>6, d = i&63;
        float e = Ag.eps_u[((size_t)(b0+row)*TT + t)*64 + d];
        float u = e*__expf(0.5f*ul_p[i]) + um_p[i];
        lds_wr(ubuf, row, d, 128, u);
      }
    }
    __syncthreads();

    // ---- P4: generator GRU (input u, hidden g 256) ----
    f32x4 gR[2][2]={}, gZ[2][2]={}, gI[2][2]={}, gH[2][2]={};
    #pragma unroll
    for(int kt=0;kt<2;kt++){
      bf16x8 au[2];
      #pragma unroll
      for(int mt=0;mt<2;mt++) au[mt] = lds_rdA(ubuf, mt*16+lr, kt, lq, 128);
      #pragma unroll
      for(int g=0;g<3;g++)
        #pragma unroll
        for(int jt=0;jt<2;jt++){
          bf16x8 bb = *(const bf16x8*)(Ag.wih_gn + o_ihgn[g][jt] + kt*32);
          #pragma unroll
          for(int mt=0;mt<2;mt++){
            if(g==0)      gR[mt][jt]=MFMA_B16(au[mt],bb,gR[mt][jt]);
            else if(g==1) gZ[mt][jt]=MFMA_B16(au[mt],bb,gZ[mt][jt]);
            else          gI[mt][jt]=MFMA_B16(au[mt],bb,gI[mt][jt]);
          }
        }
    }
    #pragma unroll 2
    for(int kt=0;kt<8;kt++){
      bf16x8 ag2[2];
      #pragma unroll
      for(int mt=0;mt<2;mt++) ag2[mt] = lds_rdA(gbuf[pg], mt*16+lr, kt, lq, 512);
      #pragma unroll
      for(int g=0;g<3;g++)
        #pragma unroll
        for(int jt=0;jt<2;jt++){
          bf16x8 bb = *(const bf16x8*)(Ag.whh_gn + o_hhgn[g][jt] + kt*32);
          #pragma unroll
          for(int mt=0;mt<2;mt++){
            if(g==0)      gR[mt][jt]=MFMA_B16(ag2[mt],bb,gR[mt][jt]);
            else if(g==1) gZ[mt][jt]=MFMA_B16(ag2[mt],bb,gZ[mt][jt]);
            else          gH[mt][jt]=MFMA_B16(ag2[mt],bb,gH[mt][jt]);
          }
        }
    }
    #pragma unroll
    for(int mt=0;mt<2;mt++)
      #pragma unroll
      for(int jt=0;jt<2;jt++)
        #pragma unroll
        for(int rr=0;rr<4;rr++){
          float r = sig_f(gR[mt][jt][rr] + bgn_rz0[jt]);
          float z = sig_f(gZ[mt][jt][rr] + bgn_rz1[jt]);
          float nn= tanh_f(gI[mt][jt][rr] + bgn_in[jt] + r*(gH[mt][jt][rr] + bgn_hn[jt]));
          float gv = (1.f-z)*nn + z*g_old[mt][jt][rr];
          gv = fminf(fmaxf(gv, 0.f), 5.f);
          g_old[mt][jt][rr] = gv;
          lds_wr(gbuf[1-pg], mt*16+lq*4+rr, w*32+jt*16+lr, 512, gv);
        }
    __syncthreads();

    // ---- P5: f = g@W_f^T + b_f (waves 0-3) ----
    if(w<4){
      f32x4 fa[2]={};
      #pragma unroll
      for(int kt=0;kt<8;kt++){
        bf16x8 bb = *(const bf16x8*)(Ag.w_f + o_fw + kt*32);
        #pragma unroll
        for(int mt=0;mt<2;mt++){
          bf16x8 aa = lds_rdA(gbuf[1-pg], mt*16+lr, kt, lq, 512);
          fa[mt] = MFMA_B16(aa, bb, fa[mt]);
        }
      }
      #pragma unroll
      for(int mt=0;mt<2;mt++)
        #pragma unroll
        for(int rr=0;rr<4;rr++){
          int row = mt*16 + lq*4 + rr;
          float v = fa[mt][rr] + bff;
          Ag.o_f[((size_t)(b0+row)*TT + t)*64 + du] = v;
          lds_wr(fbuf[1-pf], row, du, 128, v);
        }
    }
    __syncthreads();
    pc^=1; pg^=1; pf^=1;
  }
}

// ---------------- K5: rates = exp(clip(factors@W_r^T + b_r, -5, 5)) (f32 VALU) ----------------
__global__ void rates_k(const float* __restrict__ fac, const float* __restrict__ Wr,
                        const float* __restrict__ br, float* __restrict__ out){
  const int total = 512*200*256;
  int i = blockIdx.x*blockDim.x + threadIdx.x;
  int st = gridDim.x*blockDim.x;
  for(; i<total; i+=st){
    int row = i>>8, n = i&255;
    const float4* fp=(const float4*)(fac + (size_t)row*64);
    const float4* wp=(const float4*)(Wr  + (size_t)n*64);
    float a = 0.f;
    #pragma unroll
    for(int k=0;k<16;k++){
      float4 f=fp[k], ww=wp[k];
      a += f.x*ww.x + f.y*ww.y + f.z*ww.z + f.w*ww.w;
    }
    a += br[n];
    a = fminf(fmaxf(a, -5.f), 5.f);
    out[i] = __expf(a);
  }
}

// ---------------- host ----------------
extern "C" void kernel_launch(void* const* d_in, const int* in_sizes, int n_in,
                              void* d_out, int out_size, void* d_ws, size_t ws_size,
                              hipStream_t stream){
  (void)in_sizes; (void)n_in; (void)out_size; (void)ws_size;
  const float* x      = (const float*)d_in[0];
  const float* eps_g0 = (const float*)d_in[1];
  const float* eps_u  = (const float*)d_in[2];
  const float* Wih_f[6]; const float* Whh_f[6]; const float* bih[6]; const float* bhh[6];
  for(int c=0;c<6;c++){
    Wih_f[c]=(const float*)d_in[3+4*c]; Whh_f[c]=(const float*)d_in[4+4*c];
    bih[c]  =(const float*)d_in[5+4*c]; bhh[c]  =(const float*)d_in[6+4*c];
  }
  const float* W_g0m=(const float*)d_in[27]; const float* b_g0m=(const float*)d_in[28];
  const float* W_g0v=(const float*)d_in[29]; const float* b_g0v=(const float*)d_in[30];
  const float* W_um =(const float*)d_in[31]; const float* b_um =(const float*)d_in[32];
  const float* W_uv =(const float*)d_in[33]; const float* b_uv =(const float*)d_in[34];
  const float* W_f  =(const float*)d_in[35]; const float* b_f  =(const float*)d_in[36];
  const float* W_r  =(const float*)d_in[37]; const float* b_r  =(const float*)d_in[38];

  // workspace layout (~190 MB)
  char* ws = (char*)d_ws; size_t off = 0;
  auto alloc = [&](size_t bytes)->char*{
    char* p = ws + off; off = (off + bytes + 255) & ~(size_t)255; return p;
  };
  static const int ih_sz[6] = {768*256,768*256,768*256,768*256,384*576,768*64};
  static const int hh_sz[6] = {768*256,768*256,768*256,768*256,384*128,768*256};
  __bf16* wih_b[6]; __bf16* whh_b[6];
  for(int c=0;c<6;c++){
    wih_b[c]=(__bf16*)alloc((size_t)ih_sz[c]*2);
    whh_b[c]=(__bf16*)alloc((size_t)hh_sz[c]*2);
  }
  __bf16* wum_b=(__bf16*)alloc(64*128*2);
  __bf16* wuv_b=(__bf16*)alloc(64*128*2);
  __bf16* wf_b =(__bf16*)alloc(64*256*2);
  __bf16* henc =(__bf16*)alloc((size_t)200*512*512*2);
  __bf16* gict =(__bf16*)alloc((size_t)200*512*384*2);
  float*  hencg=(float*)alloc((size_t)512*512*4);
  float*  g0   =(float*)alloc((size_t)512*256*4);

  // K0: weight conversions
  for(int c=0;c<6;c++){
    cvt_bf16<<<128,256,0,stream>>>(Wih_f[c], wih_b[c], ih_sz[c]);
    cvt_bf16<<<128,256,0,stream>>>(Whh_f[c], whh_b[c], hh_sz[c]);
  }
  cvt_bf16<<<32,256,0,stream>>>(W_um, wum_b, 64*128);
  cvt_bf16<<<32,256,0,stream>>>(W_uv, wuv_b, 64*128);
  cvt_bf16<<<32,256,0,stream>>>(W_f,  wf_b,  64*256);

  // K1: encoder scans
  EncArgs ea;
  ea.x = x;
  for(int c=0;c<4;c++){ ea.wih[c]=wih_b[c]; ea.whh[c]=whh_b[c]; ea.bih[c]=bih[c]; ea.bhh[c]=bhh[c]; }
  ea.henc = henc; ea.hencg = hencg;
  enc_scan<<<dim3(16,4),512,0,stream>>>(ea);

  float* out = (float*)d_out;
  float* o_mean = out;
  float* o_logv = out + 131072;
  float* o_um   = out + 262144;
  float* o_ul   = out + 6815744;
  float* o_f    = out + 13369344;
  float* o_r    = out + 19922944;

  // K2: g0 head
  g0_kernel<<<512,256,0,stream>>>(hencg, W_g0m,b_g0m, W_g0v,b_g0v, eps_g0, o_mean,o_logv, g0);

  // K3: ct input projection from h_enc_c
  gict_gemm<<<800,256,0,stream>>>(henc, wih_b[4], gict);

  // K4: generator scan
  GenArgs ga;
  ga.wih_ct=wih_b[4]; ga.whh_ct=whh_b[4]; ga.wih_gn=wih_b[5]; ga.whh_gn=whh_b[5];
  ga.w_um=wum_b; ga.w_uv=wuv_b; ga.w_f=wf_b;
  ga.bih_ct=bih[4]; ga.bhh_ct=bhh[4]; ga.bih_gn=bih[5]; ga.bhh_gn=bhh[5];
  ga.b_um=b_um; ga.b_uv=b_uv; ga.b_f=b_f;
  ga.gih=gict; ga.g0=g0; ga.eps_u=eps_u;
  ga.o_um=o_um; ga.o_ul=o_ul; ga.o_f=o_f;
  gen_scan<<<16,512,0,stream>>>(ga);

  // K5: rates
  rates_k<<<8192,256,0,stream>>>(o_f, W_r, b_r, o_r);
}